// Round 18
// baseline (125.135 us; speedup 1.0000x reference)
//
#include <hip/hip_runtime.h>
#include <hip/hip_bf16.h>
#include <stdint.h>

typedef __bf16 bf16_t;
typedef _Float16 h16_t;
typedef __bf16 bf16x8 __attribute__((ext_vector_type(8)));
typedef _Float16 h16x8 __attribute__((ext_vector_type(8)));
typedef float f32x4 __attribute__((ext_vector_type(4)));
typedef float f32x16 __attribute__((ext_vector_type(16)));
typedef int i32x2 __attribute__((ext_vector_type(2)));

#define B_ 4
#define N_ 4096
#define C_ 256
#define D3_ 768
// AEXP = (1/sqrt(32)) * log2(e); folded into Q at QKV epilogue -> logits in log2 domain.
#define AEXP 0.2550348757f
// f16 magic-Schraudolph (computed in f32): y = fmaf(x, 1024, 2^23 + 15360);
// low16(bits(y)) == round(1024*x + 15360) == f16 bit pattern of ~exp2(x) (±3%).
#define MAGICH 8403968.0f

__device__ __forceinline__ f32x4 mfma16(bf16x8 a, bf16x8 b, f32x4 c) {
    return __builtin_amdgcn_mfma_f32_16x16x32_bf16(a, b, c, 0, 0, 0);
}
__device__ __forceinline__ f32x16 mfma32(bf16x8 a, bf16x8 b, f32x16 c) {
    return __builtin_amdgcn_mfma_f32_32x32x16_bf16(a, b, c, 0, 0, 0);
}
__device__ __forceinline__ f32x16 mfma32h(h16x8 a, h16x8 b, f32x16 c) {
    return __builtin_amdgcn_mfma_f32_32x32x16_f16(a, b, c, 0, 0, 0);
}
// pack LOW-16s of two dwords: dst = (a_lo16 << 16) | b_lo16
__device__ __forceinline__ int pk2lo(int a, int b) {
    return (int)__builtin_amdgcn_perm((unsigned)a, (unsigned)b, 0x05040100u);
}
__device__ __forceinline__ int pkaddh(int a, int b) {
    int r; asm("v_pk_add_f16 %0, %1, %2" : "=v"(r) : "v"(a), "v"(b)); return r;
}
union H8 { int i[4]; h16x8 v; };

// one 32-j chunk: QK^T(bf16) -> f16 magic-exp2 -> P frags -> PV(f16);
// denominator partial accumulated in packed f16 (lacc MFMA amortized by caller).
// st elements pinned to VGPRs: VALU cannot read AGPRs, so an AGPR-resident st
// costs 16 v_accvgpr_read per step — the empty asm forces VGPR allocation.
__device__ __forceinline__ void qt_step(bf16x8 kA, bf16x8 kB, h16x8 vA, h16x8 vB,
                                        bf16x8 qa, bf16x8 qb_,
                                        const f32x16& zacc,
                                        f32x16& oacc, H8& pfs, bool first) {
    __builtin_amdgcn_s_setprio(1);
    f32x16 st = mfma32(kB, qb_, zacc);
    st = mfma32(kA, qa, st);
    __builtin_amdgcn_s_setprio(0);
    int y[16];
#pragma unroll
    for (int i = 0; i < 16; ++i) {
        float v = st[i];
        asm("" : "+v"(v));           // pin to VGPR side
        y[i] = __builtin_bit_cast(int, fmaf(v, 1024.0f, MAGICH));
    }
    int a0 = pk2lo(y[1], y[0]), a1 = pk2lo(y[3], y[2]);
    int b0 = pk2lo(y[5], y[4]), b1 = pk2lo(y[7], y[6]);
    i32x2 r0 = __builtin_amdgcn_permlane32_swap(a0, b0, false, false);
    i32x2 r1 = __builtin_amdgcn_permlane32_swap(a1, b1, false, false);
    int c0 = pk2lo(y[9], y[8]), c1 = pk2lo(y[11], y[10]);
    int d0 = pk2lo(y[13], y[12]), d1 = pk2lo(y[15], y[14]);
    i32x2 r2 = __builtin_amdgcn_permlane32_swap(c0, d0, false, false);
    i32x2 r3 = __builtin_amdgcn_permlane32_swap(c1, d1, false, false);
    H8 pf0, pf1;
    pf0.i[0] = r0.x; pf0.i[1] = r1.x; pf0.i[2] = r0.y; pf0.i[3] = r1.y;
    pf1.i[0] = r2.x; pf1.i[1] = r3.x; pf1.i[2] = r2.y; pf1.i[3] = r3.y;
#pragma unroll
    for (int j = 0; j < 4; ++j) {
        int s = pkaddh(pf0.i[j], pf1.i[j]);
        pfs.i[j] = first ? s : pkaddh(pfs.i[j], s);
    }
    __builtin_amdgcn_s_setprio(1);
    oacc = mfma32h(vA, pf0.v, oacc);
    oacc = mfma32h(vB, pf1.v, oacc);
    __builtin_amdgcn_s_setprio(0);
}

union PK4 { uint2 u2; bf16_t h[4]; };
union PKH { uint2 u2; h16_t h[4]; };

// ---------------- fused prep: 64x64 f32x4 x-transpose + weight transposes + stats ----------------
__global__ void prep(const float* __restrict__ x, const float* __restrict__ wqkv,
                     const float* __restrict__ wproj,
                     bf16_t* __restrict__ xT, bf16_t* __restrict__ Wt,
                     bf16_t* __restrict__ Wpt, float* __restrict__ stats) {
    __shared__ float tile[64][68];
    int bid = blockIdx.x;
    int t = threadIdx.x;
    if (bid < 1024) {                 // x [B,C,N] f32 -> xT [B,N,C] bf16, 64x64 tiles
        int nt = bid & 63, ct = (bid >> 6) & 3, b = bid >> 8;
        int n0 = nt * 64, c0 = ct * 64;
        const float* xp = x + ((size_t)b * C_ + c0) * N_ + n0;
#pragma unroll
        for (int p = 0; p < 4; ++p) {
            int row = p * 16 + (t >> 4);     // c within tile
            int col = (t & 15) * 4;          // n within tile
            *reinterpret_cast<f32x4*>(&tile[row][col]) =
                *reinterpret_cast<const f32x4*>(&xp[(size_t)row * N_ + col]);
        }
        __syncthreads();
        int n = t >> 2;
        bf16_t* op = xT + ((size_t)b * N_ + n0 + n) * C_ + c0;
#pragma unroll
        for (int q = 0; q < 2; ++q) {
            int cb = q * 4 + (t & 3);
            uint32_t d[4];
#pragma unroll
            for (int i = 0; i < 4; ++i) {
                union { uint32_t u; bf16_t h[2]; } pk;
                pk.h[0] = (bf16_t)tile[cb * 8 + 2 * i][n];
                pk.h[1] = (bf16_t)tile[cb * 8 + 2 * i + 1][n];
                d[i] = pk.u;
            }
            *reinterpret_cast<uint4*>(&op[cb * 8]) = *reinterpret_cast<const uint4*>(d);
        }
    } else {                          // weight transposes + stats zero
        int tt = (bid - 1024) * 256 + t;
        if (tt < D3_ * C_) {          // Wt[c][k] = wqkv[k][c]
            int c = tt >> 8, k = tt & 255;
            Wt[tt] = (bf16_t)wqkv[k * D3_ + c];
        }
        if (tt < C_ * C_) {           // Wpt[c][k] = wproj[k][c]
            int c = tt >> 8, k = tt & 255;
            Wpt[tt] = (bf16_t)wproj[k * C_ + c];
        }
        if (tt < B_ * 32 * 2) stats[tt] = 0.f;
    }
}

// ---------------- QKV GEMM: 128x128 LDS tile, BK=64 (half the barriers), 4 waves 2x2 ----------------
// grid (128, 6). Q pre-scaled by AEXP; V chunk-tiled f16: Vt[bh][n>>5][d][n&31].
__global__ __launch_bounds__(256) void gemm_qkv(
    const bf16_t* __restrict__ xT, const bf16_t* __restrict__ Wt,
    const float* __restrict__ bqkv,
    bf16_t* __restrict__ Q, bf16_t* __restrict__ K, h16_t* __restrict__ Vt)
{
    __shared__ __align__(16) bf16_t Al[128][72];
    __shared__ __align__(16) bf16_t Bl[128][72];
    int m0 = blockIdx.x * 128, c0 = blockIdx.y * 128;
    int t = threadIdx.x;
    int w = t >> 6, l = t & 63, li = l & 15, lg = l >> 4;
    int wr = w >> 1, wc = w & 1;
    int srow = t >> 3, scol = (t & 7) * 8;
    f32x4 acc[4][4] = {};
    for (int k0 = 0; k0 < C_; k0 += 64) {
#pragma unroll
        for (int p = 0; p < 4; ++p) {
            int row = p * 32 + srow;
            *reinterpret_cast<bf16x8*>(&Al[row][scol]) =
                *reinterpret_cast<const bf16x8*>(&xT[(size_t)(m0 + row) * C_ + k0 + scol]);
            *reinterpret_cast<bf16x8*>(&Bl[row][scol]) =
                *reinterpret_cast<const bf16x8*>(&Wt[(size_t)(c0 + row) * C_ + k0 + scol]);
        }
        __syncthreads();
#pragma unroll
        for (int kk = 0; kk < 2; ++kk) {
            bf16x8 afr[4], bfr[4];
#pragma unroll
            for (int fr = 0; fr < 4; ++fr)
                afr[fr] = *reinterpret_cast<const bf16x8*>(&Al[wr * 64 + fr * 16 + li][kk * 32 + lg * 8]);
#pragma unroll
            for (int fc = 0; fc < 4; ++fc)
                bfr[fc] = *reinterpret_cast<const bf16x8*>(&Bl[wc * 64 + fc * 16 + li][kk * 32 + lg * 8]);
#pragma unroll
            for (int fr = 0; fr < 4; ++fr)
#pragma unroll
                for (int fc = 0; fc < 4; ++fc)
                    acc[fr][fc] = mfma16(afr[fr], bfr[fc], acc[fr][fc]);
        }
        __syncthreads();
    }
#pragma unroll
    for (int fr = 0; fr < 4; ++fr) {
        int mb = m0 + wr * 64 + fr * 16 + lg * 4;
        int b = mb >> 12, n = mb & 4095;
#pragma unroll
        for (int fc = 0; fc < 4; ++fc) {
            int col = c0 + wc * 64 + fc * 16 + li;
            float bias = bqkv[col];
            int sec = col >> 8, cc = col & 255;
            int h = cc >> 5, d = cc & 31;
            if (sec == 2) {              // V chunk-tiled f16: [bh][n>>5][d][n&31]
                PKH pk;
#pragma unroll
                for (int r = 0; r < 4; ++r) pk.h[r] = (h16_t)(acc[fr][fc][r] + bias);
                size_t vaddr = (((size_t)((b << 3) + h) * 128 + (n >> 5)) * 32 + d) * 32 + (n & 31);
                *reinterpret_cast<uint2*>(&Vt[vaddr]) = pk.u2;
            } else {                     // Q / K: [b,h][n][d]; Q pre-scaled by AEXP
                bf16_t* dst = (sec == 0) ? Q : K;
                float vs = (sec == 0) ? AEXP : 1.0f;
                size_t base = ((size_t)((b << 3) + h) * N_ + n) * 32 + d;
#pragma unroll
                for (int r = 0; r < 4; ++r) dst[base + (size_t)r * 32] = (bf16_t)((acc[fr][fc][r] + bias) * vs);
            }
        }
    }
}

// ---------------- flash attention: no LDS; 2 q-tiles/wave share each K/V fragment; ----------------
// ---------------- 2 waves/SIMD; 2-set register prefetch; f16 magic-exp2;             ----------------
// ---------------- denominator MFMA amortized over 2 chunks (pfs in packed f16)       ----------------
__global__ __launch_bounds__(256, 2) void attn(
    const bf16_t* __restrict__ Q, const bf16_t* __restrict__ Kg,
    const h16_t* __restrict__ Vt, bf16_t* __restrict__ O)
{
    int id = blockIdx.x;
    int wg = (id & 7) * 64 + (id >> 3);           // XCD swizzle: 64 blocks (4 bh) per XCD
    int bh = wg >> 4, qb = wg & 15;
    int t = threadIdx.x, w = t >> 6, l = t & 63;
    int lo = l & 31, hi = l >> 5;
    const bf16_t* Qp = Q + (size_t)bh * N_ * 32;
    int qbase = qb * 256 + w * 64;                // + qt*32 + lo
    bf16x8 q0a = *reinterpret_cast<const bf16x8*>(&Qp[(size_t)(qbase +  0 + lo) * 32 + hi * 8]);
    bf16x8 q0b = *reinterpret_cast<const bf16x8*>(&Qp[(size_t)(qbase +  0 + lo) * 32 + 16 + hi * 8]);
    bf16x8 q1a = *reinterpret_cast<const bf16x8*>(&Qp[(size_t)(qbase + 32 + lo) * 32 + hi * 8]);
    bf16x8 q1b = *reinterpret_cast<const bf16x8*>(&Qp[(size_t)(qbase + 32 + lo) * 32 + 16 + hi * 8]);
    f32x16 o0 = {}, o1 = {};
    f32x16 la0 = {}, la1 = {};
    const f32x16 zacc = {};
    h16x8 ones;
#pragma unroll
    for (int u = 0; u < 8; ++u) ones[u] = (h16_t)1.0f;
    const bf16_t* kp = Kg + (size_t)bh * N_ * 32 + (size_t)lo * 32 + hi * 8;
    const h16_t* vp = Vt + (size_t)bh * (N_ * 32) + (size_t)lo * 32 + hi * 8;  // chunk-tiled
    // prologue: chunks 0 and 1
    bf16x8 k0A = *reinterpret_cast<const bf16x8*>(kp);
    bf16x8 k0B = *reinterpret_cast<const bf16x8*>(kp + 16);
    h16x8  v0A = *reinterpret_cast<const h16x8*>(vp);
    h16x8  v0B = *reinterpret_cast<const h16x8*>(vp + 16);
    bf16x8 k1A = *reinterpret_cast<const bf16x8*>(kp + 1024);
    bf16x8 k1B = *reinterpret_cast<const bf16x8*>(kp + 1024 + 16);
    h16x8  v1A = *reinterpret_cast<const h16x8*>(vp + 1024);
    h16x8  v1B = *reinterpret_cast<const h16x8*>(vp + 1024 + 16);
    kp += 2048; vp += 2048;                        // -> chunk c+2 addresses
    for (int c = 0; c < N_ / 32; c += 2) {
        H8 pfs0, pfs1;
        // ---- chunk c (set 0): both q-tiles share k0*/v0*; then prefetch chunk c+2 ----
        qt_step(k0A, k0B, v0A, v0B, q0a, q0b, zacc, o0, pfs0, true);
        qt_step(k0A, k0B, v0A, v0B, q1a, q1b, zacc, o1, pfs1, true);
        k0A = *reinterpret_cast<const bf16x8*>(kp);
        k0B = *reinterpret_cast<const bf16x8*>(kp + 16);
        v0A = *reinterpret_cast<const h16x8*>(vp);
        v0B = *reinterpret_cast<const h16x8*>(vp + 16);
        // ---- chunk c+1 (set 1): then amortized lacc + prefetch chunk c+3 ----
        qt_step(k1A, k1B, v1A, v1B, q0a, q0b, zacc, o0, pfs0, false);
        qt_step(k1A, k1B, v1A, v1B, q1a, q1b, zacc, o1, pfs1, false);
        __builtin_amdgcn_s_setprio(1);
        la0 = mfma32h(ones, pfs0.v, la0);
        la1 = mfma32h(ones, pfs1.v, la1);
        __builtin_amdgcn_s_setprio(0);
        k1A = *reinterpret_cast<const bf16x8*>(kp + 1024);
        k1B = *reinterpret_cast<const bf16x8*>(kp + 1024 + 16);
        v1A = *reinterpret_cast<const h16x8*>(vp + 1024);
        v1B = *reinterpret_cast<const h16x8*>(vp + 1024 + 16);
        kp += 2048; vp += 2048;
    }
    // epilogue: O^T[d][i] / l(i) -> O[b][n][h*32+d]; d = rq*8 + hi*4 + (reg&3)
    int b = bh >> 3, h = bh & 7;
#pragma unroll
    for (int qt = 0; qt < 2; ++qt) {
        f32x16 oc = (qt == 0) ? o0 : o1;
        f32x16 lc = (qt == 0) ? la0 : la1;
        float inv_l = 1.f / lc[0];
        int qrow = qbase + qt * 32 + lo;
#pragma unroll
        for (int rq = 0; rq < 4; ++rq) {
            PK4 pk;
#pragma unroll
            for (int r = 0; r < 4; ++r) pk.h[r] = (bf16_t)(oc[rq * 4 + r] * inv_l);
            int d = rq * 8 + hi * 4;
            *reinterpret_cast<uint2*>(&O[(((size_t)b * N_ + qrow) * 8 + h) * 32 + d]) = pk.u2;
        }
    }
}

// ---------------- proj GEMM (64x64 LDS tile) + bias + residual(x) -> z bf16; ----------------
// ---------------- group stats via block-level LDS reduction (16 atomics/block) ----------------
__global__ __launch_bounds__(256) void gemm_proj(
    const bf16_t* __restrict__ O, const bf16_t* __restrict__ Wpt,
    const float* __restrict__ bproj, const float* __restrict__ x,
    bf16_t* __restrict__ z, float* __restrict__ stats)
{
    __shared__ __align__(16) bf16_t Al[64][40];
    __shared__ __align__(16) bf16_t Bl[64][40];
    __shared__ float red[4][4][2][2];   // [wave][ct][gi][s,s2]
    int m0 = blockIdx.x * 64, c0 = blockIdx.y * 64;
    int t = threadIdx.x;
    int w = t >> 6, l = t & 63, li = l & 15, lg = l >> 4;
    int srow = t >> 2, scol = (t & 3) * 8;
    f32x4 acc[4] = {};
    for (int k0 = 0; k0 < C_; k0 += 32) {
        *reinterpret_cast<bf16x8*>(&Al[srow][scol]) =
            *reinterpret_cast<const bf16x8*>(&O[(size_t)(m0 + srow) * C_ + k0 + scol]);
        *reinterpret_cast<bf16x8*>(&Bl[srow][scol]) =
            *reinterpret_cast<const bf16x8*>(&Wpt[(size_t)(c0 + srow) * C_ + k0 + scol]);
        __syncthreads();
        bf16x8 af = *reinterpret_cast<const bf16x8*>(&Al[w * 16 + li][lg * 8]);
#pragma unroll
        for (int ct = 0; ct < 4; ++ct) {
            bf16x8 bf = *reinterpret_cast<const bf16x8*>(&Bl[ct * 16 + li][lg * 8]);
            acc[ct] = mfma16(af, bf, acc[ct]);
        }
        __syncthreads();
    }
    int mb = m0 + w * 16 + lg * 4;
    int b = mb >> 12, n = mb & 4095;
#pragma unroll
    for (int ct = 0; ct < 4; ++ct) {
        int c = c0 + ct * 16 + li;
        float bias = bproj[c];
        size_t xoff = ((size_t)b * C_ + c) * N_ + n;
        f32x4 xv = *reinterpret_cast<const f32x4*>(&x[xoff]);
        PK4 pk;
        float s = 0.f, s2 = 0.f;
#pragma unroll
        for (int r = 0; r < 4; ++r) {
            float v = acc[ct][r] + bias + xv[r];
            pk.h[r] = (bf16_t)v; s += v; s2 += v * v;
        }
        *reinterpret_cast<uint2*>(&z[xoff]) = pk.u2;
        s  += __shfl_xor(s, 16, 64);  s  += __shfl_xor(s, 32, 64);
        s2 += __shfl_xor(s2, 16, 64); s2 += __shfl_xor(s2, 32, 64);
        s  += __shfl_xor(s, 1, 64);  s  += __shfl_xor(s, 2, 64);  s  += __shfl_xor(s, 4, 64);
        s2 += __shfl_xor(s2, 1, 64); s2 += __shfl_xor(s2, 2, 64); s2 += __shfl_xor(s2, 4, 64);
        if (lg == 0 && (li & 7) == 0) {
            red[w][ct][li >> 3][0] = s;
            red[w][ct][li >> 3][1] = s2;
        }
    }
    __syncthreads();
    if (t < 16) {                    // t -> (ct, gi, which)
        int ct = t >> 2, gi = (t >> 1) & 1, v = t & 1;
        float sum = red[0][ct][gi][v] + red[1][ct][gi][v] +
                    red[2][ct][gi][v] + red[3][ct][gi][v];
        int bb = m0 >> 12;
        int g = ((c0 + ct * 16 + gi * 8) >> 3);
        atomicAdd(&stats[((bb << 5) + g) * 2 + v], sum);
    }
}

// ---------------- GroupNorm normalize: z [B,C,N] bf16 -> out [B,C,H,W] f32 ----------------
__global__ void gnorm(const bf16_t* __restrict__ z, const float* __restrict__ stats,
                      const float* __restrict__ gamma, const float* __restrict__ beta,
                      float* __restrict__ out)
{
    size_t idx = ((size_t)blockIdx.x * 256 + threadIdx.x) * 8;
    int b = (int)(idx >> 20);
    int c = (int)((idx >> 12) & 255);
    int g = c >> 3;
    float s = stats[((b << 5) + g) * 2], s2 = stats[((b << 5) + g) * 2 + 1];
    const float inv = 1.f / 32768.f;
    float mean = s * inv;
    float var = s2 * inv - mean * mean;
    float rs = rsqrtf(var + 1e-5f);
    float ga = gamma[c] * rs;
    float be = beta[c];
#pragma unroll
    for (int p = 0; p < 2; ++p) {
        PK4 pz;
        pz.u2 = *reinterpret_cast<const uint2*>(&z[idx + p * 4]);
        f32x4 o;
#pragma unroll
        for (int r = 0; r < 4; ++r) o[r] = ((float)pz.h[r] - mean) * ga + be;
        *reinterpret_cast<f32x4*>(&out[idx + p * 4]) = o;
    }
}

extern "C" void kernel_launch(void* const* d_in, const int* in_sizes, int n_in,
                              void* d_out, int out_size, void* d_ws, size_t ws_size,
                              hipStream_t stream) {
    (void)in_sizes; (void)n_in; (void)out_size; (void)ws_size;
    const float* x     = (const float*)d_in[0];
    const float* wqkv  = (const float*)d_in[1];
    const float* bqkv  = (const float*)d_in[2];
    const float* wproj = (const float*)d_in[3];
    const float* bproj = (const float*)d_in[4];
    const float* gamma = (const float*)d_in[5];
    const float* beta  = (const float*)d_in[6];
    float* out = (float*)d_out;

    char* ws = (char*)d_ws;
    const size_t SZ_BNC2 = (size_t)B_ * N_ * C_ * 2;
    size_t off = 0;
    bf16_t* xT  = (bf16_t*)(ws + off); off += SZ_BNC2;
    bf16_t* Wt  = (bf16_t*)(ws + off); off += (size_t)D3_ * C_ * 2;
    bf16_t* Qb  = (bf16_t*)(ws + off); off += SZ_BNC2;
    bf16_t* Kb  = (bf16_t*)(ws + off); off += SZ_BNC2;
    h16_t*  Vtb = (h16_t*)(ws + off);  off += SZ_BNC2;
    bf16_t* Ob  = (bf16_t*)(ws + off); off += SZ_BNC2;
    bf16_t* Wpt = (bf16_t*)(ws + off); off += (size_t)C_ * C_ * 2;
    float*  stats = (float*)(ws + off); off += 1024;
    bf16_t* zb = (bf16_t*)d_ws;   // aliases xT (dead by gemm_proj); 8.4 MB

    prep<<<1792, 256, 0, stream>>>(x, wqkv, wproj, xT, Wt, Wpt, stats);
    gemm_qkv<<<dim3(128, 6), 256, 0, stream>>>(xT, Wt, bqkv, Qb, Kb, Vtb);
    attn<<<512, 256, 0, stream>>>(Qb, Kb, Vtb, Ob);
    gemm_proj<<<dim3(256, 4), 256, 0, stream>>>(Ob, Wpt, bproj, x, zb, stats);
    gnorm<<<2048, 256, 0, stream>>>(zb, stats, gamma, beta, out);
}

// Round 20
// 122.009 us; speedup vs baseline: 1.0256x; 1.0256x over previous
//
#include <hip/hip_runtime.h>
#include <hip/hip_bf16.h>
#include <stdint.h>

typedef __bf16 bf16_t;
typedef _Float16 h16_t;
typedef __bf16 bf16x8 __attribute__((ext_vector_type(8)));
typedef _Float16 h16x8 __attribute__((ext_vector_type(8)));
typedef float f32x4 __attribute__((ext_vector_type(4)));
typedef float f32x16 __attribute__((ext_vector_type(16)));
typedef int i32x2 __attribute__((ext_vector_type(2)));

#define B_ 4
#define N_ 4096
#define C_ 256
#define D3_ 768
// AEXP = (1/sqrt(32)) * log2(e); folded into Q at QKV epilogue -> logits in log2 domain.
#define AEXP 0.2550348757f
// f16 magic-Schraudolph (computed in f32): y = fmaf(x, 1024, 2^23 + 15360);
// low16(bits(y)) == round(1024*x + 15360) == f16 bit pattern of ~exp2(x) (±3%).
#define MAGICH 8403968.0f

__device__ __forceinline__ f32x4 mfma16(bf16x8 a, bf16x8 b, f32x4 c) {
    return __builtin_amdgcn_mfma_f32_16x16x32_bf16(a, b, c, 0, 0, 0);
}
__device__ __forceinline__ f32x16 mfma32(bf16x8 a, bf16x8 b, f32x16 c) {
    return __builtin_amdgcn_mfma_f32_32x32x16_bf16(a, b, c, 0, 0, 0);
}
__device__ __forceinline__ f32x16 mfma32h(h16x8 a, h16x8 b, f32x16 c) {
    return __builtin_amdgcn_mfma_f32_32x32x16_f16(a, b, c, 0, 0, 0);
}
// pack LOW-16s of two dwords: dst = (a_lo16 << 16) | b_lo16
__device__ __forceinline__ int pk2lo(int a, int b) {
    return (int)__builtin_amdgcn_perm((unsigned)a, (unsigned)b, 0x05040100u);
}
__device__ __forceinline__ int pkaddh(int a, int b) {
    int r; asm("v_pk_add_f16 %0, %1, %2" : "=v"(r) : "v"(a), "v"(b)); return r;
}
union H8 { int i[4]; h16x8 v; };

// one 32-j chunk: QK^T(bf16) -> f16 magic-exp2 -> P frags -> PV(f16);
// denominator partial accumulated in packed f16 (lacc MFMA amortized by caller)
__device__ __forceinline__ void qt_step(bf16x8 kA, bf16x8 kB, h16x8 vA, h16x8 vB,
                                        bf16x8 qa, bf16x8 qb_,
                                        const f32x16& zacc,
                                        f32x16& oacc, H8& pfs, bool first) {
    __builtin_amdgcn_s_setprio(1);
    f32x16 st = mfma32(kB, qb_, zacc);
    st = mfma32(kA, qa, st);
    __builtin_amdgcn_s_setprio(0);
    int y[16];
#pragma unroll
    for (int i = 0; i < 16; ++i)
        y[i] = __builtin_bit_cast(int, fmaf(st[i], 1024.0f, MAGICH));
    int a0 = pk2lo(y[1], y[0]), a1 = pk2lo(y[3], y[2]);
    int b0 = pk2lo(y[5], y[4]), b1 = pk2lo(y[7], y[6]);
    i32x2 r0 = __builtin_amdgcn_permlane32_swap(a0, b0, false, false);
    i32x2 r1 = __builtin_amdgcn_permlane32_swap(a1, b1, false, false);
    int c0 = pk2lo(y[9], y[8]), c1 = pk2lo(y[11], y[10]);
    int d0 = pk2lo(y[13], y[12]), d1 = pk2lo(y[15], y[14]);
    i32x2 r2 = __builtin_amdgcn_permlane32_swap(c0, d0, false, false);
    i32x2 r3 = __builtin_amdgcn_permlane32_swap(c1, d1, false, false);
    H8 pf0, pf1;
    pf0.i[0] = r0.x; pf0.i[1] = r1.x; pf0.i[2] = r0.y; pf0.i[3] = r1.y;
    pf1.i[0] = r2.x; pf1.i[1] = r3.x; pf1.i[2] = r2.y; pf1.i[3] = r3.y;
#pragma unroll
    for (int j = 0; j < 4; ++j) {
        int s = pkaddh(pf0.i[j], pf1.i[j]);
        pfs.i[j] = first ? s : pkaddh(pfs.i[j], s);
    }
    __builtin_amdgcn_s_setprio(1);
    oacc = mfma32h(vA, pf0.v, oacc);
    oacc = mfma32h(vB, pf1.v, oacc);
    __builtin_amdgcn_s_setprio(0);
}

union PK4 { uint2 u2; bf16_t h[4]; };
union PKH { uint2 u2; h16_t h[4]; };

// ---------------- fused prep: 64x64 f32x4 x-transpose + weight transposes + stats ----------------
__global__ void prep(const float* __restrict__ x, const float* __restrict__ wqkv,
                     const float* __restrict__ wproj,
                     bf16_t* __restrict__ xT, bf16_t* __restrict__ Wt,
                     bf16_t* __restrict__ Wpt, float* __restrict__ stats) {
    __shared__ float tile[64][68];
    int bid = blockIdx.x;
    int t = threadIdx.x;
    if (bid < 1024) {                 // x [B,C,N] f32 -> xT [B,N,C] bf16, 64x64 tiles
        int nt = bid & 63, ct = (bid >> 6) & 3, b = bid >> 8;
        int n0 = nt * 64, c0 = ct * 64;
        const float* xp = x + ((size_t)b * C_ + c0) * N_ + n0;
#pragma unroll
        for (int p = 0; p < 4; ++p) {
            int row = p * 16 + (t >> 4);     // c within tile
            int col = (t & 15) * 4;          // n within tile
            *reinterpret_cast<f32x4*>(&tile[row][col]) =
                *reinterpret_cast<const f32x4*>(&xp[(size_t)row * N_ + col]);
        }
        __syncthreads();
        int n = t >> 2;
        bf16_t* op = xT + ((size_t)b * N_ + n0 + n) * C_ + c0;
#pragma unroll
        for (int q = 0; q < 2; ++q) {
            int cb = q * 4 + (t & 3);
            uint32_t d[4];
#pragma unroll
            for (int i = 0; i < 4; ++i) {
                union { uint32_t u; bf16_t h[2]; } pk;
                pk.h[0] = (bf16_t)tile[cb * 8 + 2 * i][n];
                pk.h[1] = (bf16_t)tile[cb * 8 + 2 * i + 1][n];
                d[i] = pk.u;
            }
            *reinterpret_cast<uint4*>(&op[cb * 8]) = *reinterpret_cast<const uint4*>(d);
        }
    } else {                          // weight transposes + stats zero
        int tt = (bid - 1024) * 256 + t;
        if (tt < D3_ * C_) {          // Wt[c][k] = wqkv[k][c]
            int c = tt >> 8, k = tt & 255;
            Wt[tt] = (bf16_t)wqkv[k * D3_ + c];
        }
        if (tt < C_ * C_) {           // Wpt[c][k] = wproj[k][c]
            int c = tt >> 8, k = tt & 255;
            Wpt[tt] = (bf16_t)wproj[k * C_ + c];
        }
        if (tt < B_ * 32 * 2) stats[tt] = 0.f;
    }
}

// ---------------- QKV GEMM: 128x128 LDS tile, BK=32, 4 waves 2x2, acc[4][4]/wave ----------------
// grid (128, 6). Q pre-scaled by AEXP; V chunk-tiled f16: Vt[bh][n>>5][d][n&31].
__global__ __launch_bounds__(256) void gemm_qkv(
    const bf16_t* __restrict__ xT, const bf16_t* __restrict__ Wt,
    const float* __restrict__ bqkv,
    bf16_t* __restrict__ Q, bf16_t* __restrict__ K, h16_t* __restrict__ Vt)
{
    __shared__ __align__(16) bf16_t Al[128][40];
    __shared__ __align__(16) bf16_t Bl[128][40];
    int m0 = blockIdx.x * 128, c0 = blockIdx.y * 128;
    int t = threadIdx.x;
    int w = t >> 6, l = t & 63, li = l & 15, lg = l >> 4;
    int wr = w >> 1, wc = w & 1;
    int srow = t >> 2, scol = (t & 3) * 8;
    f32x4 acc[4][4] = {};
    for (int k0 = 0; k0 < C_; k0 += 32) {
        *reinterpret_cast<bf16x8*>(&Al[srow][scol]) =
            *reinterpret_cast<const bf16x8*>(&xT[(size_t)(m0 + srow) * C_ + k0 + scol]);
        *reinterpret_cast<bf16x8*>(&Al[srow + 64][scol]) =
            *reinterpret_cast<const bf16x8*>(&xT[(size_t)(m0 + srow + 64) * C_ + k0 + scol]);
        *reinterpret_cast<bf16x8*>(&Bl[srow][scol]) =
            *reinterpret_cast<const bf16x8*>(&Wt[(size_t)(c0 + srow) * C_ + k0 + scol]);
        *reinterpret_cast<bf16x8*>(&Bl[srow + 64][scol]) =
            *reinterpret_cast<const bf16x8*>(&Wt[(size_t)(c0 + srow + 64) * C_ + k0 + scol]);
        __syncthreads();
        bf16x8 afr[4], bfr[4];
#pragma unroll
        for (int fr = 0; fr < 4; ++fr)
            afr[fr] = *reinterpret_cast<const bf16x8*>(&Al[wr * 64 + fr * 16 + li][lg * 8]);
#pragma unroll
        for (int fc = 0; fc < 4; ++fc)
            bfr[fc] = *reinterpret_cast<const bf16x8*>(&Bl[wc * 64 + fc * 16 + li][lg * 8]);
#pragma unroll
        for (int fr = 0; fr < 4; ++fr)
#pragma unroll
            for (int fc = 0; fc < 4; ++fc)
                acc[fr][fc] = mfma16(afr[fr], bfr[fc], acc[fr][fc]);
        __syncthreads();
    }
#pragma unroll
    for (int fr = 0; fr < 4; ++fr) {
        int mb = m0 + wr * 64 + fr * 16 + lg * 4;
        int b = mb >> 12, n = mb & 4095;
#pragma unroll
        for (int fc = 0; fc < 4; ++fc) {
            int col = c0 + wc * 64 + fc * 16 + li;
            float bias = bqkv[col];
            int sec = col >> 8, cc = col & 255;
            int h = cc >> 5, d = cc & 31;
            if (sec == 2) {              // V chunk-tiled f16: [bh][n>>5][d][n&31]
                PKH pk;
#pragma unroll
                for (int r = 0; r < 4; ++r) pk.h[r] = (h16_t)(acc[fr][fc][r] + bias);
                size_t vaddr = (((size_t)((b << 3) + h) * 128 + (n >> 5)) * 32 + d) * 32 + (n & 31);
                *reinterpret_cast<uint2*>(&Vt[vaddr]) = pk.u2;
            } else {                     // Q / K: [b,h][n][d]; Q pre-scaled by AEXP
                bf16_t* dst = (sec == 0) ? Q : K;
                float vs = (sec == 0) ? AEXP : 1.0f;
                size_t base = ((size_t)((b << 3) + h) * N_ + n) * 32 + d;
#pragma unroll
                for (int r = 0; r < 4; ++r) dst[base + (size_t)r * 32] = (bf16_t)((acc[fr][fc][r] + bias) * vs);
            }
        }
    }
}

// ---------------- flash attention: no LDS; 2 q-tiles/wave share each K/V fragment; ----------------
// ---------------- 2 waves/SIMD; 2-set register prefetch; f16 magic-exp2;             ----------------
// ---------------- denominator MFMA amortized over 2 chunks (pfs in packed f16)       ----------------
__global__ __launch_bounds__(256, 2) void attn(
    const bf16_t* __restrict__ Q, const bf16_t* __restrict__ Kg,
    const h16_t* __restrict__ Vt, bf16_t* __restrict__ O)
{
    int id = blockIdx.x;
    int wg = (id & 7) * 64 + (id >> 3);           // XCD swizzle: 64 blocks (4 bh) per XCD
    int bh = wg >> 4, qb = wg & 15;
    int t = threadIdx.x, w = t >> 6, l = t & 63;
    int lo = l & 31, hi = l >> 5;
    const bf16_t* Qp = Q + (size_t)bh * N_ * 32;
    int qbase = qb * 256 + w * 64;                // + qt*32 + lo
    bf16x8 q0a = *reinterpret_cast<const bf16x8*>(&Qp[(size_t)(qbase +  0 + lo) * 32 + hi * 8]);
    bf16x8 q0b = *reinterpret_cast<const bf16x8*>(&Qp[(size_t)(qbase +  0 + lo) * 32 + 16 + hi * 8]);
    bf16x8 q1a = *reinterpret_cast<const bf16x8*>(&Qp[(size_t)(qbase + 32 + lo) * 32 + hi * 8]);
    bf16x8 q1b = *reinterpret_cast<const bf16x8*>(&Qp[(size_t)(qbase + 32 + lo) * 32 + 16 + hi * 8]);
    f32x16 o0 = {}, o1 = {};
    f32x16 la0 = {}, la1 = {};
    const f32x16 zacc = {};
    h16x8 ones;
#pragma unroll
    for (int u = 0; u < 8; ++u) ones[u] = (h16_t)1.0f;
    const bf16_t* kp = Kg + (size_t)bh * N_ * 32 + (size_t)lo * 32 + hi * 8;
    const h16_t* vp = Vt + (size_t)bh * (N_ * 32) + (size_t)lo * 32 + hi * 8;  // chunk-tiled
    // prologue: chunks 0 and 1
    bf16x8 k0A = *reinterpret_cast<const bf16x8*>(kp);
    bf16x8 k0B = *reinterpret_cast<const bf16x8*>(kp + 16);
    h16x8  v0A = *reinterpret_cast<const h16x8*>(vp);
    h16x8  v0B = *reinterpret_cast<const h16x8*>(vp + 16);
    bf16x8 k1A = *reinterpret_cast<const bf16x8*>(kp + 1024);
    bf16x8 k1B = *reinterpret_cast<const bf16x8*>(kp + 1024 + 16);
    h16x8  v1A = *reinterpret_cast<const h16x8*>(vp + 1024);
    h16x8  v1B = *reinterpret_cast<const h16x8*>(vp + 1024 + 16);
    kp += 2048; vp += 2048;                        // -> chunk c+2 addresses
    for (int c = 0; c < N_ / 32; c += 2) {
        H8 pfs0, pfs1;
        // ---- chunk c (set 0): both q-tiles share k0*/v0*; then prefetch chunk c+2 ----
        qt_step(k0A, k0B, v0A, v0B, q0a, q0b, zacc, o0, pfs0, true);
        qt_step(k0A, k0B, v0A, v0B, q1a, q1b, zacc, o1, pfs1, true);
        k0A = *reinterpret_cast<const bf16x8*>(kp);
        k0B = *reinterpret_cast<const bf16x8*>(kp + 16);
        v0A = *reinterpret_cast<const h16x8*>(vp);
        v0B = *reinterpret_cast<const h16x8*>(vp + 16);
        // ---- chunk c+1 (set 1): then amortized lacc + prefetch chunk c+3 ----
        qt_step(k1A, k1B, v1A, v1B, q0a, q0b, zacc, o0, pfs0, false);
        qt_step(k1A, k1B, v1A, v1B, q1a, q1b, zacc, o1, pfs1, false);
        __builtin_amdgcn_s_setprio(1);
        la0 = mfma32h(ones, pfs0.v, la0);
        la1 = mfma32h(ones, pfs1.v, la1);
        __builtin_amdgcn_s_setprio(0);
        k1A = *reinterpret_cast<const bf16x8*>(kp + 1024);
        k1B = *reinterpret_cast<const bf16x8*>(kp + 1024 + 16);
        v1A = *reinterpret_cast<const h16x8*>(vp + 1024);
        v1B = *reinterpret_cast<const h16x8*>(vp + 1024 + 16);
        kp += 2048; vp += 2048;
    }
    // epilogue: O^T[d][i] / l(i) -> O[b][n][h*32+d]; d = rq*8 + hi*4 + (reg&3)
    int b = bh >> 3, h = bh & 7;
#pragma unroll
    for (int qt = 0; qt < 2; ++qt) {
        f32x16 oc = (qt == 0) ? o0 : o1;
        f32x16 lc = (qt == 0) ? la0 : la1;
        float inv_l = 1.f / lc[0];
        int qrow = qbase + qt * 32 + lo;
#pragma unroll
        for (int rq = 0; rq < 4; ++rq) {
            PK4 pk;
#pragma unroll
            for (int r = 0; r < 4; ++r) pk.h[r] = (bf16_t)(oc[rq * 4 + r] * inv_l);
            int d = rq * 8 + hi * 4;
            *reinterpret_cast<uint2*>(&O[(((size_t)b * N_ + qrow) * 8 + h) * 32 + d]) = pk.u2;
        }
    }
}

// ---------------- proj GEMM (64x64 LDS tile) + bias + residual(x) -> z bf16; ----------------
// ---------------- group stats via block-level LDS reduction (16 atomics/block) ----------------
__global__ __launch_bounds__(256) void gemm_proj(
    const bf16_t* __restrict__ O, const bf16_t* __restrict__ Wpt,
    const float* __restrict__ bproj, const float* __restrict__ x,
    bf16_t* __restrict__ z, float* __restrict__ stats)
{
    __shared__ __align__(16) bf16_t Al[64][40];
    __shared__ __align__(16) bf16_t Bl[64][40];
    __shared__ float red[4][4][2][2];   // [wave][ct][gi][s,s2]
    int m0 = blockIdx.x * 64, c0 = blockIdx.y * 64;
    int t = threadIdx.x;
    int w = t >> 6, l = t & 63, li = l & 15, lg = l >> 4;
    int srow = t >> 2, scol = (t & 3) * 8;
    f32x4 acc[4] = {};
    for (int k0 = 0; k0 < C_; k0 += 32) {
        *reinterpret_cast<bf16x8*>(&Al[srow][scol]) =
            *reinterpret_cast<const bf16x8*>(&O[(size_t)(m0 + srow) * C_ + k0 + scol]);
        *reinterpret_cast<bf16x8*>(&Bl[srow][scol]) =
            *reinterpret_cast<const bf16x8*>(&Wpt[(size_t)(c0 + srow) * C_ + k0 + scol]);
        __syncthreads();
        bf16x8 af = *reinterpret_cast<const bf16x8*>(&Al[w * 16 + li][lg * 8]);
#pragma unroll
        for (int ct = 0; ct < 4; ++ct) {
            bf16x8 bf = *reinterpret_cast<const bf16x8*>(&Bl[ct * 16 + li][lg * 8]);
            acc[ct] = mfma16(af, bf, acc[ct]);
        }
        __syncthreads();
    }
    int mb = m0 + w * 16 + lg * 4;
    int b = mb >> 12, n = mb & 4095;
#pragma unroll
    for (int ct = 0; ct < 4; ++ct) {
        int c = c0 + ct * 16 + li;
        float bias = bproj[c];
        size_t xoff = ((size_t)b * C_ + c) * N_ + n;
        f32x4 xv = *reinterpret_cast<const f32x4*>(&x[xoff]);
        PK4 pk;
        float s = 0.f, s2 = 0.f;
#pragma unroll
        for (int r = 0; r < 4; ++r) {
            float v = acc[ct][r] + bias + xv[r];
            pk.h[r] = (bf16_t)v; s += v; s2 += v * v;
        }
        *reinterpret_cast<uint2*>(&z[xoff]) = pk.u2;
        s  += __shfl_xor(s, 16, 64);  s  += __shfl_xor(s, 32, 64);
        s2 += __shfl_xor(s2, 16, 64); s2 += __shfl_xor(s2, 32, 64);
        s  += __shfl_xor(s, 1, 64);  s  += __shfl_xor(s, 2, 64);  s  += __shfl_xor(s, 4, 64);
        s2 += __shfl_xor(s2, 1, 64); s2 += __shfl_xor(s2, 2, 64); s2 += __shfl_xor(s2, 4, 64);
        if (lg == 0 && (li & 7) == 0) {
            red[w][ct][li >> 3][0] = s;
            red[w][ct][li >> 3][1] = s2;
        }
    }
    __syncthreads();
    if (t < 16) {                    // t -> (ct, gi, which)
        int ct = t >> 2, gi = (t >> 1) & 1, v = t & 1;
        float sum = red[0][ct][gi][v] + red[1][ct][gi][v] +
                    red[2][ct][gi][v] + red[3][ct][gi][v];
        int bb = m0 >> 12;
        int g = ((c0 + ct * 16 + gi * 8) >> 3);
        atomicAdd(&stats[((bb << 5) + g) * 2 + v], sum);
    }
}

// ---------------- GroupNorm normalize: z [B,C,N] bf16 -> out [B,C,H,W] f32 ----------------
__global__ void gnorm(const bf16_t* __restrict__ z, const float* __restrict__ stats,
                      const float* __restrict__ gamma, const float* __restrict__ beta,
                      float* __restrict__ out)
{
    size_t idx = ((size_t)blockIdx.x * 256 + threadIdx.x) * 8;
    int b = (int)(idx >> 20);
    int c = (int)((idx >> 12) & 255);
    int g = c >> 3;
    float s = stats[((b << 5) + g) * 2], s2 = stats[((b << 5) + g) * 2 + 1];
    const float inv = 1.f / 32768.f;
    float mean = s * inv;
    float var = s2 * inv - mean * mean;
    float rs = rsqrtf(var + 1e-5f);
    float ga = gamma[c] * rs;
    float be = beta[c];
#pragma unroll
    for (int p = 0; p < 2; ++p) {
        PK4 pz;
        pz.u2 = *reinterpret_cast<const uint2*>(&z[idx + p * 4]);
        f32x4 o;
#pragma unroll
        for (int r = 0; r < 4; ++r) o[r] = ((float)pz.h[r] - mean) * ga + be;
        *reinterpret_cast<f32x4*>(&out[idx + p * 4]) = o;
    }
}

extern "C" void kernel_launch(void* const* d_in, const int* in_sizes, int n_in,
                              void* d_out, int out_size, void* d_ws, size_t ws_size,
                              hipStream_t stream) {
    (void)in_sizes; (void)n_in; (void)out_size; (void)ws_size;
    const float* x     = (const float*)d_in[0];
    const float* wqkv  = (const float*)d_in[1];
    const float* bqkv  = (const float*)d_in[2];
    const float* wproj = (const float*)d_in[3];
    const float* bproj = (const float*)d_in[4];
    const float* gamma = (const float*)d_in[5];
    const float* beta  = (const float*)d_in[6];
    float* out = (float*)d_out;

    char* ws = (char*)d_ws;
    const size_t SZ_BNC2 = (size_t)B_ * N_ * C_ * 2;
    size_t off = 0;
    bf16_t* xT  = (bf16_t*)(ws + off); off += SZ_BNC2;
    bf16_t* Wt  = (bf16_t*)(ws + off); off += (size_t)D3_ * C_ * 2;
    bf16_t* Qb  = (bf16_t*)(ws + off); off += SZ_BNC2;
    bf16_t* Kb  = (bf16_t*)(ws + off); off += SZ_BNC2;
    h16_t*  Vtb = (h16_t*)(ws + off);  off += SZ_BNC2;
    bf16_t* Ob  = (bf16_t*)(ws + off); off += SZ_BNC2;
    bf16_t* Wpt = (bf16_t*)(ws + off); off += (size_t)C_ * C_ * 2;
    float*  stats = (float*)(ws + off); off += 1024;
    bf16_t* zb = (bf16_t*)d_ws;   // aliases xT (dead by gemm_proj); 8.4 MB

    prep<<<1792, 256, 0, stream>>>(x, wqkv, wproj, xT, Wt, Wpt, stats);
    gemm_qkv<<<dim3(128, 6), 256, 0, stream>>>(xT, Wt, bqkv, Qb, Kb, Vtb);
    attn<<<512, 256, 0, stream>>>(Qb, Kb, Vtb, Ob);
    gemm_proj<<<dim3(256, 4), 256, 0, stream>>>(Ob, Wpt, bproj, x, zb, stats);
    gnorm<<<2048, 256, 0, stream>>>(zb, stats, gamma, beta, out);
}